// Round 2
// baseline (650.457 us; speedup 1.0000x reference)
//
#include <hip/hip_runtime.h>
#include <math.h>

#define BB 16
#define SS 4096
#define HH 1024
#define CC 64

typedef __attribute__((ext_vector_type(4))) float f32x4;
typedef __attribute__((ext_vector_type(8))) short s16x8;
typedef __attribute__((ext_vector_type(4))) unsigned int u32x4;

__device__ __forceinline__ ushort f2bf(float x) {
    union { float f; unsigned u; } un; un.f = x;
    unsigned r = (un.u + 0x7FFFu + ((un.u >> 16) & 1u)) >> 16;
    return (ushort)r;
}
__device__ __forceinline__ float bf2f(ushort h) {
    union { unsigned u; float f; } un; un.u = ((unsigned)h) << 16; return un.f;
}

// pack the high 16 bits of two dwords: result = {lo16 = v0>>16, hi16 = v1>>16}
__device__ __forceinline__ unsigned hipack(unsigned v1, unsigned v0) {
    return __builtin_amdgcn_perm(v1, v0, 0x07060302u);
}

// split 8 fp32 -> bf16 hi (round-half-up) + bf16 lo (exact residual, truncated)
__device__ __forceinline__ void cvt8(f32x4 f0, f32x4 f1, s16x8& hi, s16x8& lo) {
    u32x4 u0 = __builtin_bit_cast(u32x4, f0);
    u32x4 u1 = __builtin_bit_cast(u32x4, f1);
    u32x4 b0 = u0 + 0x8000u;
    u32x4 b1 = u1 + 0x8000u;
    f32x4 m0 = __builtin_bit_cast(f32x4, b0 & 0xFFFF0000u);
    f32x4 m1 = __builtin_bit_cast(f32x4, b1 & 0xFFFF0000u);
    u32x4 r0 = __builtin_bit_cast(u32x4, f0 - m0);
    u32x4 r1 = __builtin_bit_cast(u32x4, f1 - m1);
    u32x4 h = { hipack(b0.y, b0.x), hipack(b0.w, b0.z),
                hipack(b1.y, b1.x), hipack(b1.w, b1.z) };
    u32x4 l = { hipack(r0.y, r0.x), hipack(r0.w, r0.z),
                hipack(r1.y, r1.x), hipack(r1.w, r1.z) };
    hi = __builtin_bit_cast(s16x8, h);
    lo = __builtin_bit_cast(s16x8, l);
}

// ---------------- prep: querys -> hi/lo bf16
__global__ __launch_bounds__(256) void prep_querys_kernel(
    const float* __restrict__ q, ushort* __restrict__ qhi, ushort* __restrict__ qlo)
{
    const int i4 = blockIdx.x * 256 + threadIdx.x;   // float4 index, 16384 total
    const float4 v = ((const float4*)q)[i4];
    ushort4 h, l;
    h.x = f2bf(v.x); l.x = f2bf(v.x - bf2f(h.x));
    h.y = f2bf(v.y); l.y = f2bf(v.y - bf2f(h.y));
    h.z = f2bf(v.z); l.z = f2bf(v.z - bf2f(h.z));
    h.w = f2bf(v.w); l.w = f2bf(v.w - bf2f(h.w));
    ((ushort4*)qhi)[i4] = h;
    ((ushort4*)qlo)[i4] = l;
}

// ---------------- scores[b][c][s]: barrier-free, LDS-free reg-streamed split-bf16 MFMA.
// 32s x 64c tile/block, 4 waves in 2(row-group) x 2(col-half); each wave 16s x 32c.
// Grid = 128x16 = 2048 blocks -> 8 waves/SIMD. Also emits hid_hi (bf16 of hidden).
__global__ __launch_bounds__(256) void scores_kernel(
    const float* __restrict__ hidden, const ushort* __restrict__ qhi,
    const ushort* __restrict__ qlo, float* __restrict__ scores,
    ushort* __restrict__ hid_hi)
{
    const int b  = blockIdx.y;
    const int s0 = blockIdx.x * 32;
    const int t  = threadIdx.x;
    const int w = t >> 6, lane = t & 63, col = lane & 15, quad = lane >> 4;
    const int rg = w & 1;    // row group (s)
    const int ch = w >> 1;   // col half (c)

    // A-fragment row owned by this lane (m = lane&15, k = quad*8..+8)
    const int r0 = s0 + rg * 16 + col;
    const float* a0p = hidden + ((size_t)b * SS + r0) * HH + quad * 8;
    ushort* h0p = hid_hi + ((size_t)b * SS + r0) * HH + quad * 8;
    const ushort* qbh = qhi + (size_t)(ch * 32 + col) * HH + quad * 8;
    const ushort* qbl = qlo + (size_t)(ch * 32 + col) * HH + quad * 8;

    f32x4 acc[2];
    acc[0] = (f32x4){0.f, 0.f, 0.f, 0.f};
    acc[1] = (f32x4){0.f, 0.f, 0.f, 0.f};

    f32x4 Aa0, Aa1, Ab0, Ab1;

#define LOADA(P0, P1, K) do { \
    P0 = *(const f32x4*)(a0p + (K)); \
    P1 = *(const f32x4*)(a0p + (K) + 4); } while (0)

#define SCOMP(P0, P1, K) do { \
    s16x8 ah0, al0; \
    cvt8(P0, P1, ah0, al0); \
    if (ch == 0) *(s16x8*)(h0p + (K)) = ah0; \
    _Pragma("unroll") \
    for (int nt = 0; nt < 2; ++nt) { \
        const s16x8 bh = *(const s16x8*)(qbh + nt * 16 * HH + (K)); \
        const s16x8 bl = *(const s16x8*)(qbl + nt * 16 * HH + (K)); \
        acc[nt] = __builtin_amdgcn_mfma_f32_16x16x32_bf16(ah0, bh, acc[nt], 0, 0, 0); \
        acc[nt] = __builtin_amdgcn_mfma_f32_16x16x32_bf16(ah0, bl, acc[nt], 0, 0, 0); \
        acc[nt] = __builtin_amdgcn_mfma_f32_16x16x32_bf16(al0, bh, acc[nt], 0, 0, 0); \
    } } while (0)

    LOADA(Aa0, Aa1, 0);
    for (int k0 = 0; k0 < HH; k0 += 64) {
        LOADA(Ab0, Ab1, k0 + 32);
        SCOMP(Aa0, Aa1, k0);
        if (k0 + 64 < HH) LOADA(Aa0, Aa1, k0 + 64);
        SCOMP(Ab0, Ab1, k0 + 32);
    }
#undef LOADA
#undef SCOMP

    // C/D: col=lane&15 -> c (n), row=quad*4+reg -> s (m)
#pragma unroll
    for (int nt = 0; nt < 2; ++nt) {
        const int c = ch * 32 + nt * 16 + col;
        const int s = s0 + rg * 16 + quad * 4;
        *(f32x4*)&scores[((size_t)(b * CC + c)) * SS + s] = acc[nt];
    }
}

// ---------------- softmax over s, writes bf16 factor
__global__ __launch_bounds__(256) void softmax_kernel(
    const float* __restrict__ scores, ushort* __restrict__ factor)
{
    const float* p = scores + (size_t)blockIdx.x * SS;
    ushort* f = factor + (size_t)blockIdx.x * SS;
    const int t = threadIdx.x;
    float4 v[4];
    float m = -3.0e38f;
#pragma unroll
    for (int i = 0; i < 4; ++i) {
        v[i] = *(const float4*)&p[t * 4 + i * 1024];
        m = fmaxf(m, fmaxf(fmaxf(v[i].x, v[i].y), fmaxf(v[i].z, v[i].w)));
    }
#pragma unroll
    for (int off = 1; off < 64; off <<= 1) m = fmaxf(m, __shfl_xor(m, off));
    __shared__ float redm[4];
    __shared__ float reds[4];
    const int wave = t >> 6, lane = t & 63;
    if (lane == 0) redm[wave] = m;
    __syncthreads();
    m = fmaxf(fmaxf(redm[0], redm[1]), fmaxf(redm[2], redm[3]));

    float sum = 0.0f;
#pragma unroll
    for (int i = 0; i < 4; ++i) {
        v[i].x = __expf(v[i].x - m); v[i].y = __expf(v[i].y - m);
        v[i].z = __expf(v[i].z - m); v[i].w = __expf(v[i].w - m);
        sum += (v[i].x + v[i].y) + (v[i].z + v[i].w);
    }
#pragma unroll
    for (int off = 1; off < 64; off <<= 1) sum += __shfl_xor(sum, off);
    if (lane == 0) reds[wave] = sum;
    __syncthreads();
    sum = (reds[0] + reds[1]) + (reds[2] + reds[3]);
    const float inv = 1.0f / sum;
#pragma unroll
    for (int i = 0; i < 4; ++i) {
        ushort4 o;
        o.x = f2bf(v[i].x * inv); o.y = f2bf(v[i].y * inv);
        o.z = f2bf(v[i].z * inv); o.w = f2bf(v[i].w * inv);
        ((ushort4*)f)[t + i * 256] = o;
    }
}

// ---------------- pool: parts[ks][b][c][h], barrier-free, LDS-free. Reads bf16 hid_hi.
// 64c x 32h tile/block, split-4 over S. Grid = 32x16x4 = 2048 blocks -> 8 waves/SIMD.
__global__ __launch_bounds__(256) void pool_kernel(
    const ushort* __restrict__ hid_hi, const ushort* __restrict__ factor,
    float* __restrict__ parts)
{
    const int b  = blockIdx.y;
    const int h0 = blockIdx.x * 32;
    const int ks = blockIdx.z;
    const int sbeg = ks * (SS / 4);
    const int t = threadIdx.x;
    const int w = t >> 6, lane = t & 63, col = lane & 15, quad = lane >> 4;

    f32x4 acc[2];
    acc[0] = (f32x4){0.f, 0.f, 0.f, 0.f};
    acc[1] = (f32x4){0.f, 0.f, 0.f, 0.f};

    // A-frag (factor): m = c = w*16+col, k = s (contiguous)
    const ushort* fptr = factor + ((size_t)(b * CC + w * 16 + col)) * SS + sbeg + quad * 8;
    // B-frag (hidden^T): n = h = h0+nt*16+col, k = s -> scalar loads at row stride HH
    const ushort* hp = hid_hi + ((size_t)b * SS + sbeg + quad * 8) * HH + h0 + col;

    ushort ra[2][8], rb[2][8];
    s16x8 faA, faB;

#define PLOAD(R, FA, SC) do { \
    FA = *(const s16x8*)(fptr + (SC)); \
    _Pragma("unroll") for (int nt = 0; nt < 2; ++nt) \
    _Pragma("unroll") for (int j = 0; j < 8; ++j) \
        R[nt][j] = hp[(size_t)((SC) + j) * HH + nt * 16]; } while (0)

#define PCOMP(R, FA) do { \
    _Pragma("unroll") for (int nt = 0; nt < 2; ++nt) { \
        u32x4 d = { (unsigned)R[nt][0] | ((unsigned)R[nt][1] << 16), \
                    (unsigned)R[nt][2] | ((unsigned)R[nt][3] << 16), \
                    (unsigned)R[nt][4] | ((unsigned)R[nt][5] << 16), \
                    (unsigned)R[nt][6] | ((unsigned)R[nt][7] << 16) }; \
        const s16x8 hb = __builtin_bit_cast(s16x8, d); \
        acc[nt] = __builtin_amdgcn_mfma_f32_16x16x32_bf16(FA, hb, acc[nt], 0, 0, 0); \
    } } while (0)

    PLOAD(ra, faA, 0);
    for (int sc = 0; sc < SS / 4; sc += 64) {
        PLOAD(rb, faB, sc + 32);
        PCOMP(ra, faA);
        if (sc + 64 < SS / 4) PLOAD(ra, faA, sc + 64);
        PCOMP(rb, faB);
    }
#undef PLOAD
#undef PCOMP

    float* dst = parts + (size_t)ks * (BB * CC * HH) + (size_t)b * (CC * HH);
#pragma unroll
    for (int nt = 0; nt < 2; ++nt) {
        const int h = h0 + nt * 16 + col;
#pragma unroll
        for (int r = 0; r < 4; ++r) {
            const int c = w * 16 + quad * 4 + r;
            dst[(size_t)c * HH + h] = acc[nt][r];
        }
    }
}

// ---------------- final reduce of 4 split-K partials
__global__ __launch_bounds__(256) void reduce4_kernel(
    const float* __restrict__ parts, float* __restrict__ out)
{
    const int i = blockIdx.x * 256 + threadIdx.x;   // float4 index
    const float4* p = (const float4*)parts;
    const float4 a = p[i];
    const float4 b = p[i + 262144];
    const float4 c = p[i + 524288];
    const float4 d = p[i + 786432];
    float4 r;
    r.x = (a.x + b.x) + (c.x + d.x);
    r.y = (a.y + b.y) + (c.y + d.y);
    r.z = (a.z + b.z) + (c.z + d.z);
    r.w = (a.w + b.w) + (c.w + d.w);
    ((float4*)out)[i] = r;
}

extern "C" void kernel_launch(void* const* d_in, const int* in_sizes, int n_in,
                              void* d_out, int out_size, void* d_ws, size_t ws_size,
                              hipStream_t stream)
{
    const float* hidden = (const float*)d_in[0];   // [16,4096,1024] fp32
    const float* querys = (const float*)d_in[1];   // [64,1024] fp32
    float* out = (float*)d_out;

    float*  scores = (float*)d_ws;                           // 16 MiB [0,16M)
    float*  parts  = (float*)d_ws;                           // aliases scores (pool phase)
    ushort* factor = (ushort*)((char*)d_ws + (16u << 20));   // 8 MiB [16M,24M)
    ushort* qhi    = (ushort*)((char*)d_ws + (24u << 20));   // 128 KiB
    ushort* qlo    = qhi + CC * HH;                          // 128 KiB
    ushort* hid_hi = (ushort*)((char*)d_ws + (32u << 20));   // 128 MiB [32M,160M)

    prep_querys_kernel<<<dim3(CC * HH / 1024), 256, 0, stream>>>(querys, qhi, qlo);
    scores_kernel<<<dim3(SS / 32, BB), 256, 0, stream>>>(hidden, qhi, qlo, scores, hid_hi);
    softmax_kernel<<<dim3(BB * CC), 256, 0, stream>>>(scores, factor);
    pool_kernel<<<dim3(HH / 32, BB, 4), 256, 0, stream>>>(hid_hi, factor, parts);
    reduce4_kernel<<<dim3(1024), 256, 0, stream>>>(parts, out);
}

// Round 3
// 506.888 us; speedup vs baseline: 1.2832x; 1.2832x over previous
//
#include <hip/hip_runtime.h>
#include <math.h>

#define BB 16
#define SS 4096
#define HH 1024
#define CC 64

typedef __attribute__((ext_vector_type(4))) float f32x4;
typedef __attribute__((ext_vector_type(8))) short s16x8;
typedef __attribute__((ext_vector_type(4))) unsigned int u32x4;
typedef unsigned int u32;

typedef const __attribute__((address_space(1))) u32* gas_ptr;
typedef __attribute__((address_space(3))) u32* las_ptr;

// async global->LDS DMA, 16B per lane. lds must be wave-uniform; g is per-lane.
__device__ __forceinline__ void cp16(void* lds, const void* g) {
    __builtin_amdgcn_global_load_lds((gas_ptr)g, (las_ptr)(unsigned)(uintptr_t)lds, 16, 0, 0);
}

__device__ __forceinline__ ushort f2bf(float x) {
    union { float f; unsigned u; } un; un.f = x;
    unsigned r = (un.u + 0x7FFFu + ((un.u >> 16) & 1u)) >> 16;
    return (ushort)r;
}

// pack the high 16 bits of two dwords: result = {lo16 = v0>>16, hi16 = v1>>16}
__device__ __forceinline__ unsigned hipack(unsigned v1, unsigned v0) {
    return __builtin_amdgcn_perm(v1, v0, 0x07060302u);
}

// split 8 fp32 -> bf16 hi (round-half-up) + bf16 lo (residual, truncated)
__device__ __forceinline__ void cvt8(f32x4 f0, f32x4 f1, s16x8& hi, s16x8& lo) {
    u32x4 u0 = __builtin_bit_cast(u32x4, f0);
    u32x4 u1 = __builtin_bit_cast(u32x4, f1);
    u32x4 b0 = u0 + 0x8000u;
    u32x4 b1 = u1 + 0x8000u;
    f32x4 m0 = __builtin_bit_cast(f32x4, b0 & 0xFFFF0000u);
    f32x4 m1 = __builtin_bit_cast(f32x4, b1 & 0xFFFF0000u);
    u32x4 r0 = __builtin_bit_cast(u32x4, f0 - m0);
    u32x4 r1 = __builtin_bit_cast(u32x4, f1 - m1);
    u32x4 h = { hipack(b0.y, b0.x), hipack(b0.w, b0.z),
                hipack(b1.y, b1.x), hipack(b1.w, b1.z) };
    u32x4 l = { hipack(r0.y, r0.x), hipack(r0.w, r0.z),
                hipack(r1.y, r1.x), hipack(r1.w, r1.z) };
    hi = __builtin_bit_cast(s16x8, h);
    lo = __builtin_bit_cast(s16x8, l);
}

// ---------------- prep: querys -> fragment-packed bf16 hi/lo
// qpk[nt(4)][ks(32)][lane(64)][8] : lane holds (c = nt*16 + (lane&15), k = ks*32 + (lane>>4)*8 .. +8)
__global__ __launch_bounds__(256) void prep_querys_kernel(
    const float* __restrict__ q, ushort* __restrict__ qpkhi, ushort* __restrict__ qpklo)
{
    const int t = blockIdx.x * 256 + threadIdx.x;   // 0..8191
    const int lane = t & 63;
    const int ks = (t >> 6) & 31;
    const int nt = t >> 11;
    const int c = nt * 16 + (lane & 15);
    const int k = ks * 32 + (lane >> 4) * 8;
    f32x4 f0 = *(const f32x4*)&q[(size_t)c * HH + k];
    f32x4 f1 = *(const f32x4*)&q[(size_t)c * HH + k + 4];
    s16x8 hi, lo;
    cvt8(f0, f1, hi, lo);
    *(s16x8*)&qpkhi[(size_t)t * 8] = hi;
    *(s16x8*)&qpklo[(size_t)t * 8] = lo;
}

// ---------------- scores[b][c][s]: LDS-staged (global_load_lds, XOR-swizzled), split-bf16 MFMA.
// 64s x 64c per block, 4 waves, wave = 16s x 64c (nt=4). Emits hid_hi (bf16 of hidden).
__global__ __launch_bounds__(256, 4) void scores_kernel(
    const float* __restrict__ hidden, const ushort* __restrict__ qpkhi,
    const ushort* __restrict__ qpklo, float* __restrict__ scores,
    ushort* __restrict__ hid_hi)
{
    __shared__ __align__(16) float As[2][64 * 64];   // [row][64 dwords], source-pre-swizzled

    const int b  = blockIdx.y;
    const int s0 = blockIdx.x * 64;
    const int t  = threadIdx.x;
    const int w = t >> 6, lane = t & 63, col = lane & 15, quad = lane >> 4;

    const float* hb = hidden + ((size_t)b * SS + s0) * HH;

    // staging geometry: inst i covers rows i*16 + w*4 + (lane>>4), lane covers dwords (lane&15)*4
    const int st_r = w * 4 + (lane >> 4);
    const int st_d = (lane & 15) * 4;
    const int g_d  = st_d ^ ((st_r & 7) << 2);       // pre-swizzled source dword

    // fragment row owned by this lane
    const int fr  = w * 16 + col;
    const int swz = (fr & 7) << 2;
    ushort* hout = hid_hi + ((size_t)b * SS + s0 + fr) * HH;

    f32x4 acc[4];
#pragma unroll
    for (int j = 0; j < 4; ++j) acc[j] = (f32x4){0.f, 0.f, 0.f, 0.f};

#define STAGE(BUF, K0) do { \
    _Pragma("unroll") \
    for (int i = 0; i < 4; ++i) \
        cp16(&As[BUF][(i * 16 + w * 4) * 64], \
             hb + (size_t)(i * 16 + st_r) * HH + (K0) + g_d); } while (0)

    STAGE(0, 0);
    __syncthreads();

    int cur = 0;
    for (int tt = 0; tt < 16; ++tt) {
        const int k0 = tt * 64;
        if (tt + 1 < 16) STAGE(cur ^ 1, k0 + 64);

        const float* Ab = &As[cur][0];
#pragma unroll
        for (int ksub = 0; ksub < 2; ++ksub) {
            const int bdw = ksub * 32 + quad * 8;          // true dword offset of this k-slice
            const int idx0 = fr * 64 + (bdw ^ swz);
            f32x4 a0 = *(const f32x4*)&Ab[idx0];
            f32x4 a1 = *(const f32x4*)&Ab[idx0 ^ 4];
            s16x8 ah, al;
            cvt8(a0, a1, ah, al);
            *(s16x8*)&hout[k0 + bdw] = ah;
            const int ks = (k0 >> 5) + ksub;
#pragma unroll
            for (int nt = 0; nt < 4; ++nt) {
                const s16x8 bh = *(const s16x8*)&qpkhi[(size_t)((nt * 32 + ks) * 64 + lane) * 8];
                const s16x8 bl = *(const s16x8*)&qpklo[(size_t)((nt * 32 + ks) * 64 + lane) * 8];
                acc[nt] = __builtin_amdgcn_mfma_f32_16x16x32_bf16(ah, bh, acc[nt], 0, 0, 0);
                acc[nt] = __builtin_amdgcn_mfma_f32_16x16x32_bf16(ah, bl, acc[nt], 0, 0, 0);
                acc[nt] = __builtin_amdgcn_mfma_f32_16x16x32_bf16(al, bh, acc[nt], 0, 0, 0);
            }
        }
        __syncthreads();
        cur ^= 1;
    }
#undef STAGE

    // C/D: col -> c (n), quad*4+reg -> s (m)
#pragma unroll
    for (int nt = 0; nt < 4; ++nt) {
        const int c = nt * 16 + col;
        const int s = s0 + w * 16 + quad * 4;
        *(f32x4*)&scores[((size_t)(b * CC + c)) * SS + s] = acc[nt];
    }
}

// ---------------- softmax over s, writes bf16 factor
__global__ __launch_bounds__(256) void softmax_kernel(
    const float* __restrict__ scores, ushort* __restrict__ factor)
{
    const float* p = scores + (size_t)blockIdx.x * SS;
    ushort* f = factor + (size_t)blockIdx.x * SS;
    const int t = threadIdx.x;
    float4 v[4];
    float m = -3.0e38f;
#pragma unroll
    for (int i = 0; i < 4; ++i) {
        v[i] = *(const float4*)&p[t * 4 + i * 1024];
        m = fmaxf(m, fmaxf(fmaxf(v[i].x, v[i].y), fmaxf(v[i].z, v[i].w)));
    }
#pragma unroll
    for (int off = 1; off < 64; off <<= 1) m = fmaxf(m, __shfl_xor(m, off));
    __shared__ float redm[4];
    __shared__ float reds[4];
    const int wave = t >> 6, lane = t & 63;
    if (lane == 0) redm[wave] = m;
    __syncthreads();
    m = fmaxf(fmaxf(redm[0], redm[1]), fmaxf(redm[2], redm[3]));

    float sum = 0.0f;
#pragma unroll
    for (int i = 0; i < 4; ++i) {
        v[i].x = __expf(v[i].x - m); v[i].y = __expf(v[i].y - m);
        v[i].z = __expf(v[i].z - m); v[i].w = __expf(v[i].w - m);
        sum += (v[i].x + v[i].y) + (v[i].z + v[i].w);
    }
#pragma unroll
    for (int off = 1; off < 64; off <<= 1) sum += __shfl_xor(sum, off);
    if (lane == 0) reds[wave] = sum;
    __syncthreads();
    sum = (reds[0] + reds[1]) + (reds[2] + reds[3]);
    const float inv = 1.0f / sum;
#pragma unroll
    for (int i = 0; i < 4; ++i) {
        ushort4 o;
        o.x = f2bf(v[i].x * inv); o.y = f2bf(v[i].y * inv);
        o.z = f2bf(v[i].z * inv); o.w = f2bf(v[i].w * inv);
        ((ushort4*)f)[t + i * 256] = o;
    }
}

// ---------------- pool: parts[ks4][b][c][h]. hid_hi staged via global_load_lds into
// [64 s][32 h] bf16 tiles; LDS-side transpose via paired ds_read_b32 + v_perm.
// 64c x 32h per block, split-4 over S. Grid 32x16x4 = 2048 blocks.
__global__ __launch_bounds__(256, 6) void pool_kernel(
    const ushort* __restrict__ hid_hi, const ushort* __restrict__ factor,
    float* __restrict__ parts)
{
    __shared__ __align__(16) ushort Bs[2][64 * 32];  // [s][h], linear

    const int b  = blockIdx.y;
    const int h0 = blockIdx.x * 32;
    const int ks4 = blockIdx.z;
    const int sbeg = ks4 * (SS / 4);
    const int t = threadIdx.x;
    const int w = t >> 6, lane = t & 63, col = lane & 15, quad = lane >> 4;

    // staging: lane -> (s = w*16 + (lane>>2), h-chunk (lane&3)*8)
    const int st_s = w * 16 + (lane >> 2);
    const int st_h = (lane & 3) * 8;
    const ushort* hbase = hid_hi + ((size_t)b * SS + sbeg) * HH + h0;

    f32x4 acc[2];
    acc[0] = (f32x4){0.f, 0.f, 0.f, 0.f};
    acc[1] = (f32x4){0.f, 0.f, 0.f, 0.f};

    // A-frag (factor): m = c = w*16+col, k = s contiguous
    const ushort* fptr = factor + ((size_t)(b * CC + w * 16 + col)) * SS + sbeg + quad * 8;

#define PSTAGE(BUF, SC) \
    cp16(&Bs[BUF][(size_t)w * 16 * 32], hbase + (size_t)((SC) + st_s) * HH + st_h)

    PSTAGE(0, 0);
    __syncthreads();

    int cur = 0;
    for (int sc = 0; sc < SS / 4; sc += 64) {
        if (sc + 64 < SS / 4) PSTAGE(cur ^ 1, sc + 64);

        const u32* B32 = (const u32*)&Bs[cur][0];
#pragma unroll
        for (int ksub = 0; ksub < 2; ++ksub) {
            const s16x8 fa = *(const s16x8*)&fptr[sc + ksub * 32];
#pragma unroll
            for (int nt = 0; nt < 2; ++nt) {
                const int h_loc = nt * 16 + col;
                const unsigned sel = (h_loc & 1) ? 0x07060302u : 0x05040100u;
                const int base = (ksub * 32 + quad * 8) * 16 + (h_loc >> 1);
                u32 d0, d1, d2, d3;
                { u32 u0 = B32[base +  0], u1 = B32[base + 16];
                  d0 = __builtin_amdgcn_perm(u1, u0, sel); }
                { u32 u0 = B32[base + 32], u1 = B32[base + 48];
                  d1 = __builtin_amdgcn_perm(u1, u0, sel); }
                { u32 u0 = B32[base + 64], u1 = B32[base + 80];
                  d2 = __builtin_amdgcn_perm(u1, u0, sel); }
                { u32 u0 = B32[base + 96], u1 = B32[base + 112];
                  d3 = __builtin_amdgcn_perm(u1, u0, sel); }
                u32x4 dv = { d0, d1, d2, d3 };
                const s16x8 hbv = __builtin_bit_cast(s16x8, dv);
                acc[nt] = __builtin_amdgcn_mfma_f32_16x16x32_bf16(fa, hbv, acc[nt], 0, 0, 0);
            }
        }
        __syncthreads();
        cur ^= 1;
    }
#undef PSTAGE

    float* dst = parts + (size_t)ks4 * (BB * CC * HH) + (size_t)b * (CC * HH);
#pragma unroll
    for (int nt = 0; nt < 2; ++nt) {
        const int h = h0 + nt * 16 + col;
#pragma unroll
        for (int r = 0; r < 4; ++r) {
            const int c = w * 16 + quad * 4 + r;
            dst[(size_t)c * HH + h] = acc[nt][r];
        }
    }
}

// ---------------- final reduce of 4 split-K partials
__global__ __launch_bounds__(256) void reduce4_kernel(
    const float* __restrict__ parts, float* __restrict__ out)
{
    const int i = blockIdx.x * 256 + threadIdx.x;   // float4 index
    const float4* p = (const float4*)parts;
    const float4 a = p[i];
    const float4 b = p[i + 262144];
    const float4 c = p[i + 524288];
    const float4 d = p[i + 786432];
    float4 r;
    r.x = (a.x + b.x) + (c.x + d.x);
    r.y = (a.y + b.y) + (c.y + d.y);
    r.z = (a.z + b.z) + (c.z + d.z);
    r.w = (a.w + b.w) + (c.w + d.w);
    ((float4*)out)[i] = r;
}

extern "C" void kernel_launch(void* const* d_in, const int* in_sizes, int n_in,
                              void* d_out, int out_size, void* d_ws, size_t ws_size,
                              hipStream_t stream)
{
    const float* hidden = (const float*)d_in[0];   // [16,4096,1024] fp32
    const float* querys = (const float*)d_in[1];   // [64,1024] fp32
    float* out = (float*)d_out;

    float*  scores = (float*)d_ws;                           // 16 MiB [0,16M)
    float*  parts  = (float*)d_ws;                           // aliases scores (pool phase)
    ushort* factor = (ushort*)((char*)d_ws + (16u << 20));   // 8 MiB [16M,24M)
    ushort* qpkhi  = (ushort*)((char*)d_ws + (24u << 20));   // 128 KiB
    ushort* qpklo  = qpkhi + 4 * 32 * 64 * 8;                // 128 KiB
    ushort* hid_hi = (ushort*)((char*)d_ws + (32u << 20));   // 128 MiB [32M,160M)

    prep_querys_kernel<<<dim3(32), 256, 0, stream>>>(querys, qpkhi, qpklo);
    scores_kernel<<<dim3(SS / 64, BB), 256, 0, stream>>>(hidden, qpkhi, qpklo, scores, hid_hi);
    softmax_kernel<<<dim3(BB * CC), 256, 0, stream>>>(scores, factor);
    pool_kernel<<<dim3(HH / 32, BB, 4), 256, 0, stream>>>(hid_hi, factor, parts);
    reduce4_kernel<<<dim3(1024), 256, 0, stream>>>(parts, out);
}

// Round 4
// 491.941 us; speedup vs baseline: 1.3222x; 1.0304x over previous
//
#include <hip/hip_runtime.h>
#include <math.h>

#define BB 16
#define SS 4096
#define HH 1024
#define CC 64

typedef __attribute__((ext_vector_type(4))) float f32x4;
typedef __attribute__((ext_vector_type(8))) short s16x8;
typedef __attribute__((ext_vector_type(4))) unsigned int u32x4;
typedef unsigned int u32;

typedef const __attribute__((address_space(1))) u32* gas_ptr;
typedef __attribute__((address_space(3))) u32* las_ptr;

// async global->LDS DMA, 16B per lane. lds dest is wave-uniform base + lane*16; g is per-lane.
__device__ __forceinline__ void cp16(void* lds, const void* g) {
    __builtin_amdgcn_global_load_lds((gas_ptr)g, (las_ptr)(unsigned)(uintptr_t)lds, 16, 0, 0);
}

__device__ __forceinline__ ushort f2bf(float x) {
    union { float f; unsigned u; } un; un.f = x;
    unsigned r = (un.u + 0x7FFFu + ((un.u >> 16) & 1u)) >> 16;
    return (ushort)r;
}

// pack the high 16 bits of two dwords: result = {lo16 = v0>>16, hi16 = v1>>16}
__device__ __forceinline__ unsigned hipack(unsigned v1, unsigned v0) {
    return __builtin_amdgcn_perm(v1, v0, 0x07060302u);
}

// split 8 fp32 -> bf16 hi (round-half-up) + bf16 lo (residual, truncated)
__device__ __forceinline__ void cvt8(f32x4 f0, f32x4 f1, s16x8& hi, s16x8& lo) {
    u32x4 u0 = __builtin_bit_cast(u32x4, f0);
    u32x4 u1 = __builtin_bit_cast(u32x4, f1);
    u32x4 b0 = u0 + 0x8000u;
    u32x4 b1 = u1 + 0x8000u;
    f32x4 m0 = __builtin_bit_cast(f32x4, b0 & 0xFFFF0000u);
    f32x4 m1 = __builtin_bit_cast(f32x4, b1 & 0xFFFF0000u);
    u32x4 r0 = __builtin_bit_cast(u32x4, f0 - m0);
    u32x4 r1 = __builtin_bit_cast(u32x4, f1 - m1);
    u32x4 h = { hipack(b0.y, b0.x), hipack(b0.w, b0.z),
                hipack(b1.y, b1.x), hipack(b1.w, b1.z) };
    u32x4 l = { hipack(r0.y, r0.x), hipack(r0.w, r0.z),
                hipack(r1.y, r1.x), hipack(r1.w, r1.z) };
    hi = __builtin_bit_cast(s16x8, h);
    lo = __builtin_bit_cast(s16x8, l);
}

// ---------------- prep: querys -> fragment-packed bf16 hi/lo
// qpk[nt(4)][ks(32)][lane(64)][8] : lane holds (c = nt*16 + (lane&15), k = ks*32 + (lane>>4)*8 .. +8)
__global__ __launch_bounds__(256) void prep_querys_kernel(
    const float* __restrict__ q, ushort* __restrict__ qpkhi, ushort* __restrict__ qpklo)
{
    const int t = blockIdx.x * 256 + threadIdx.x;   // 0..8191
    const int lane = t & 63;
    const int ks = (t >> 6) & 31;
    const int nt = t >> 11;
    const int c = nt * 16 + (lane & 15);
    const int k = ks * 32 + (lane >> 4) * 8;
    f32x4 f0 = *(const f32x4*)&q[(size_t)c * HH + k];
    f32x4 f1 = *(const f32x4*)&q[(size_t)c * HH + k + 4];
    s16x8 hi, lo;
    cvt8(f0, f1, hi, lo);
    *(s16x8*)&qpkhi[(size_t)t * 8] = hi;
    *(s16x8*)&qpklo[(size_t)t * 8] = lo;
}

// ---------------- scores[b][c][s]: fully LDS-staged split-bf16 MFMA, BK=32 double-buffer.
// 64s x 64c per block, 4 waves, wave = 16s x 64c. A and B both via global_load_lds.
// Emits hid_hi (bf16 of hidden).
__global__ __launch_bounds__(256, 4) void scores_kernel(
    const float* __restrict__ hidden, const ushort* __restrict__ qpkhi,
    const ushort* __restrict__ qpklo, float* __restrict__ scores,
    ushort* __restrict__ hid_hi)
{
    __shared__ __align__(16) float  As[2][64 * 32];    // 8 KB each, source-pre-swizzled
    __shared__ __align__(16) ushort Bhs[2][4 * 64 * 8]; // 4 KB each, fragment-linear
    __shared__ __align__(16) ushort Bls[2][4 * 64 * 8]; // 4 KB each

    const int b  = blockIdx.y;
    const int s0 = blockIdx.x * 64;
    const int t  = threadIdx.x;
    const int w = t >> 6, lane = t & 63, col = lane & 15, quad = lane >> 4;

    const float* hb = hidden + ((size_t)b * SS + s0) * HH;

    // A staging: 8 insts of 1KB (8 rows x 32dw each), 2 per wave.
    // lane -> row = inst*8 + (lane>>3), dword ((lane&7)*4) ^ ((row&7)<<2)  [pre-swizzled source]
    const int st_r8 = lane >> 3;                        // row within 8-row group (= row&7)
    const int gA   = (((lane & 7) ^ st_r8) << 2);       // pre-swizzled dword within row

    // fragment row owned by this lane
    const int fr  = w * 16 + col;
    const int swz = (fr & 7) << 2;
    const int idxA = fr * 32 + ((quad * 8) ^ swz);
    ushort* hout = hid_hi + ((size_t)b * SS + s0 + fr) * HH;

    f32x4 acc[4];
#pragma unroll
    for (int j = 0; j < 4; ++j) acc[j] = (f32x4){0.f, 0.f, 0.f, 0.f};

#define STAGE(BUF, KS) do { \
    _Pragma("unroll") \
    for (int i = 0; i < 2; ++i) \
        cp16(&As[BUF][(w * 2 + i) * 256], \
             hb + (size_t)((w * 2 + i) * 8 + st_r8) * HH + (KS) * 32 + gA); \
    cp16(&Bhs[BUF][w * 512], qpkhi + ((size_t)(w * 32 + (KS)) * 64 + lane) * 8); \
    cp16(&Bls[BUF][w * 512], qpklo + ((size_t)(w * 32 + (KS)) * 64 + lane) * 8); } while (0)

    int cur = 0;
    STAGE(0, 0);
    __syncthreads();

    for (int ks = 0; ks < 32; ++ks) {
        if (ks + 1 < 32) STAGE(cur ^ 1, ks + 1);

        const float* Ab = &As[cur][0];
        f32x4 a0 = *(const f32x4*)&Ab[idxA];
        f32x4 a1 = *(const f32x4*)&Ab[idxA ^ 4];
        s16x8 ah, al;
        cvt8(a0, a1, ah, al);
        *(s16x8*)&hout[ks * 32 + quad * 8] = ah;
#pragma unroll
        for (int nt = 0; nt < 4; ++nt) {
            const s16x8 bh = *(const s16x8*)&Bhs[cur][nt * 512 + lane * 8];
            const s16x8 bl = *(const s16x8*)&Bls[cur][nt * 512 + lane * 8];
            acc[nt] = __builtin_amdgcn_mfma_f32_16x16x32_bf16(ah, bh, acc[nt], 0, 0, 0);
            acc[nt] = __builtin_amdgcn_mfma_f32_16x16x32_bf16(ah, bl, acc[nt], 0, 0, 0);
            acc[nt] = __builtin_amdgcn_mfma_f32_16x16x32_bf16(al, bh, acc[nt], 0, 0, 0);
        }
        __syncthreads();
        cur ^= 1;
    }
#undef STAGE

    // C/D: col -> c (n), quad*4+reg -> s (m)
#pragma unroll
    for (int nt = 0; nt < 4; ++nt) {
        const int c = nt * 16 + col;
        const int s = s0 + w * 16 + quad * 4;
        *(f32x4*)&scores[((size_t)(b * CC + c)) * SS + s] = acc[nt];
    }
}

// ---------------- softmax over s, writes bf16 factor
__global__ __launch_bounds__(256) void softmax_kernel(
    const float* __restrict__ scores, ushort* __restrict__ factor)
{
    const float* p = scores + (size_t)blockIdx.x * SS;
    ushort* f = factor + (size_t)blockIdx.x * SS;
    const int t = threadIdx.x;
    float4 v[4];
    float m = -3.0e38f;
#pragma unroll
    for (int i = 0; i < 4; ++i) {
        v[i] = *(const float4*)&p[t * 4 + i * 1024];
        m = fmaxf(m, fmaxf(fmaxf(v[i].x, v[i].y), fmaxf(v[i].z, v[i].w)));
    }
#pragma unroll
    for (int off = 1; off < 64; off <<= 1) m = fmaxf(m, __shfl_xor(m, off));
    __shared__ float redm[4];
    __shared__ float reds[4];
    const int wave = t >> 6, lane = t & 63;
    if (lane == 0) redm[wave] = m;
    __syncthreads();
    m = fmaxf(fmaxf(redm[0], redm[1]), fmaxf(redm[2], redm[3]));

    float sum = 0.0f;
#pragma unroll
    for (int i = 0; i < 4; ++i) {
        v[i].x = __expf(v[i].x - m); v[i].y = __expf(v[i].y - m);
        v[i].z = __expf(v[i].z - m); v[i].w = __expf(v[i].w - m);
        sum += (v[i].x + v[i].y) + (v[i].z + v[i].w);
    }
#pragma unroll
    for (int off = 1; off < 64; off <<= 1) sum += __shfl_xor(sum, off);
    if (lane == 0) reds[wave] = sum;
    __syncthreads();
    sum = (reds[0] + reds[1]) + (reds[2] + reds[3]);
    const float inv = 1.0f / sum;
#pragma unroll
    for (int i = 0; i < 4; ++i) {
        ushort4 o;
        o.x = f2bf(v[i].x * inv); o.y = f2bf(v[i].y * inv);
        o.z = f2bf(v[i].z * inv); o.w = f2bf(v[i].w * inv);
        ((ushort4*)f)[t + i * 256] = o;
    }
}

// ---------------- pool: parts[ks4][b][c][h]. hid_hi staged via global_load_lds into
// [64 s][32 h] bf16 tiles; LDS-side transpose via paired ds_read_b32 + v_perm.
// factor fragments register-prefetched one window ahead.
// 64c x 32h per block, split-4 over S. Grid 32x16x4 = 2048 blocks.
__global__ __launch_bounds__(256, 6) void pool_kernel(
    const ushort* __restrict__ hid_hi, const ushort* __restrict__ factor,
    float* __restrict__ parts)
{
    __shared__ __align__(16) ushort Bs[2][64 * 32];  // [s][h], linear

    const int b  = blockIdx.y;
    const int h0 = blockIdx.x * 32;
    const int ks4 = blockIdx.z;
    const int sbeg = ks4 * (SS / 4);
    const int t = threadIdx.x;
    const int w = t >> 6, lane = t & 63, col = lane & 15, quad = lane >> 4;

    // staging: lane -> (s = w*16 + (lane>>2), h-chunk (lane&3)*8)
    const int st_s = w * 16 + (lane >> 2);
    const int st_h = (lane & 3) * 8;
    const ushort* hbase = hid_hi + ((size_t)b * SS + sbeg) * HH + h0;

    f32x4 acc[2];
    acc[0] = (f32x4){0.f, 0.f, 0.f, 0.f};
    acc[1] = (f32x4){0.f, 0.f, 0.f, 0.f};

    // A-frag (factor): m = c = w*16+col, k = s contiguous
    const ushort* fptr = factor + ((size_t)(b * CC + w * 16 + col)) * SS + sbeg + quad * 8;

#define PSTAGE(BUF, SC) \
    cp16(&Bs[BUF][(size_t)w * 16 * 32], hbase + (size_t)((SC) + st_s) * HH + st_h)

    s16x8 fa0 = *(const s16x8*)&fptr[0];
    s16x8 fa1 = *(const s16x8*)&fptr[32];
    PSTAGE(0, 0);
    __syncthreads();

    int cur = 0;
    for (int sc = 0; sc < SS / 4; sc += 64) {
        s16x8 fn0, fn1;
        if (sc + 64 < SS / 4) {
            PSTAGE(cur ^ 1, sc + 64);
            fn0 = *(const s16x8*)&fptr[sc + 64];
            fn1 = *(const s16x8*)&fptr[sc + 96];
        }

        const u32* B32 = (const u32*)&Bs[cur][0];
#pragma unroll
        for (int ksub = 0; ksub < 2; ++ksub) {
            const s16x8 fa = ksub ? fa1 : fa0;
#pragma unroll
            for (int nt = 0; nt < 2; ++nt) {
                const int h_loc = nt * 16 + col;
                const unsigned sel = (h_loc & 1) ? 0x07060302u : 0x05040100u;
                const int base = (ksub * 32 + quad * 8) * 16 + (h_loc >> 1);
                u32 d0, d1, d2, d3;
                { u32 u0 = B32[base +  0], u1 = B32[base + 16];
                  d0 = __builtin_amdgcn_perm(u1, u0, sel); }
                { u32 u0 = B32[base + 32], u1 = B32[base + 48];
                  d1 = __builtin_amdgcn_perm(u1, u0, sel); }
                { u32 u0 = B32[base + 64], u1 = B32[base + 80];
                  d2 = __builtin_amdgcn_perm(u1, u0, sel); }
                { u32 u0 = B32[base + 96], u1 = B32[base + 112];
                  d3 = __builtin_amdgcn_perm(u1, u0, sel); }
                u32x4 dv = { d0, d1, d2, d3 };
                const s16x8 hbv = __builtin_bit_cast(s16x8, dv);
                acc[nt] = __builtin_amdgcn_mfma_f32_16x16x32_bf16(fa, hbv, acc[nt], 0, 0, 0);
            }
        }
        __syncthreads();
        cur ^= 1;
        fa0 = fn0;
        fa1 = fn1;
    }
#undef PSTAGE

    float* dst = parts + (size_t)ks4 * (BB * CC * HH) + (size_t)b * (CC * HH);
#pragma unroll
    for (int nt = 0; nt < 2; ++nt) {
        const int h = h0 + nt * 16 + col;
#pragma unroll
        for (int r = 0; r < 4; ++r) {
            const int c = w * 16 + quad * 4 + r;
            dst[(size_t)c * HH + h] = acc[nt][r];
        }
    }
}

// ---------------- final reduce of 4 split-K partials
__global__ __launch_bounds__(256) void reduce4_kernel(
    const float* __restrict__ parts, float* __restrict__ out)
{
    const int i = blockIdx.x * 256 + threadIdx.x;   // float4 index
    const float4* p = (const float4*)parts;
    const float4 a = p[i];
    const float4 b = p[i + 262144];
    const float4 c = p[i + 524288];
    const float4 d = p[i + 786432];
    float4 r;
    r.x = (a.x + b.x) + (c.x + d.x);
    r.y = (a.y + b.y) + (c.y + d.y);
    r.z = (a.z + b.z) + (c.z + d.z);
    r.w = (a.w + b.w) + (c.w + d.w);
    ((float4*)out)[i] = r;
}

extern "C" void kernel_launch(void* const* d_in, const int* in_sizes, int n_in,
                              void* d_out, int out_size, void* d_ws, size_t ws_size,
                              hipStream_t stream)
{
    const float* hidden = (const float*)d_in[0];   // [16,4096,1024] fp32
    const float* querys = (const float*)d_in[1];   // [64,1024] fp32
    float* out = (float*)d_out;

    float*  scores = (float*)d_ws;                           // 16 MiB [0,16M)
    float*  parts  = (float*)d_ws;                           // aliases scores (pool phase)
    ushort* factor = (ushort*)((char*)d_ws + (16u << 20));   // 8 MiB [16M,24M)
    ushort* qpkhi  = (ushort*)((char*)d_ws + (24u << 20));   // 128 KiB
    ushort* qpklo  = qpkhi + 4 * 32 * 64 * 8;                // 128 KiB
    ushort* hid_hi = (ushort*)((char*)d_ws + (32u << 20));   // 128 MiB [32M,160M)

    prep_querys_kernel<<<dim3(32), 256, 0, stream>>>(querys, qpkhi, qpklo);
    scores_kernel<<<dim3(SS / 64, BB), 256, 0, stream>>>(hidden, qpkhi, qpklo, scores, hid_hi);
    softmax_kernel<<<dim3(BB * CC), 256, 0, stream>>>(scores, factor);
    pool_kernel<<<dim3(HH / 32, BB, 4), 256, 0, stream>>>(hid_hi, factor, parts);
    reduce4_kernel<<<dim3(1024), 256, 0, stream>>>(parts, out);
}

// Round 5
// 471.830 us; speedup vs baseline: 1.3786x; 1.0426x over previous
//
#include <hip/hip_runtime.h>
#include <math.h>

#define BB 16
#define SS 4096
#define HH 1024
#define CC 64

typedef __attribute__((ext_vector_type(4))) float f32x4;
typedef __attribute__((ext_vector_type(8))) short s16x8;
typedef __attribute__((ext_vector_type(4))) unsigned int u32x4;
typedef unsigned int u32;

typedef const __attribute__((address_space(1))) u32* gas_ptr;
typedef __attribute__((address_space(3))) u32* las_ptr;

// async global->LDS DMA, 16B per lane. lds dest is wave-uniform base + lane*16; g is per-lane.
__device__ __forceinline__ void cp16(void* lds, const void* g) {
    __builtin_amdgcn_global_load_lds((gas_ptr)g, (las_ptr)(unsigned)(uintptr_t)lds, 16, 0, 0);
}

__device__ __forceinline__ ushort f2bf(float x) {
    union { float f; unsigned u; } un; un.f = x;
    unsigned r = (un.u + 0x7FFFu + ((un.u >> 16) & 1u)) >> 16;
    return (ushort)r;
}

// pack the high 16 bits of two dwords: result = {lo16 = v0>>16, hi16 = v1>>16}
__device__ __forceinline__ unsigned hipack(unsigned v1, unsigned v0) {
    return __builtin_amdgcn_perm(v1, v0, 0x07060302u);
}

// split 8 fp32 -> bf16 hi (round-half-up) + bf16 lo (residual, truncated)
__device__ __forceinline__ void cvt8(f32x4 f0, f32x4 f1, s16x8& hi, s16x8& lo) {
    u32x4 u0 = __builtin_bit_cast(u32x4, f0);
    u32x4 u1 = __builtin_bit_cast(u32x4, f1);
    u32x4 b0 = u0 + 0x8000u;
    u32x4 b1 = u1 + 0x8000u;
    f32x4 m0 = __builtin_bit_cast(f32x4, b0 & 0xFFFF0000u);
    f32x4 m1 = __builtin_bit_cast(f32x4, b1 & 0xFFFF0000u);
    u32x4 r0 = __builtin_bit_cast(u32x4, f0 - m0);
    u32x4 r1 = __builtin_bit_cast(u32x4, f1 - m1);
    u32x4 h = { hipack(b0.y, b0.x), hipack(b0.w, b0.z),
                hipack(b1.y, b1.x), hipack(b1.w, b1.z) };
    u32x4 l = { hipack(r0.y, r0.x), hipack(r0.w, r0.z),
                hipack(r1.y, r1.x), hipack(r1.w, r1.z) };
    hi = __builtin_bit_cast(s16x8, h);
    lo = __builtin_bit_cast(s16x8, l);
}

// ---------------- prep: querys -> fragment-packed bf16 hi/lo
// qpk[nt(4)][ks(32)][lane(64)][8] : lane holds (c = nt*16 + (lane&15), k = ks*32 + (lane>>4)*8 .. +8)
__global__ __launch_bounds__(256) void prep_querys_kernel(
    const float* __restrict__ q, ushort* __restrict__ qpkhi, ushort* __restrict__ qpklo)
{
    const int t = blockIdx.x * 256 + threadIdx.x;   // 0..8191
    const int lane = t & 63;
    const int ks = (t >> 6) & 31;
    const int nt = t >> 11;
    const int c = nt * 16 + (lane & 15);
    const int k = ks * 32 + (lane >> 4) * 8;
    f32x4 f0 = *(const f32x4*)&q[(size_t)c * HH + k];
    f32x4 f1 = *(const f32x4*)&q[(size_t)c * HH + k + 4];
    s16x8 hi, lo;
    cvt8(f0, f1, hi, lo);
    *(s16x8*)&qpkhi[(size_t)t * 8] = hi;
    *(s16x8*)&qpklo[(size_t)t * 8] = lo;
}

// ---------------- scores[b][c][s]: fully LDS-staged split-bf16 MFMA, BK=32 double-buffer.
// 32s x 64c per block, 4 waves = 2(rg: 16s) x 2(ch: 32c). Grid 128x16 = 2048 blocks.
// LDS 24 KB -> 6 blocks/CU. Emits hid_hi (bf16 of hidden).
__global__ __launch_bounds__(256, 6) void scores_kernel(
    const float* __restrict__ hidden, const ushort* __restrict__ qpkhi,
    const ushort* __restrict__ qpklo, float* __restrict__ scores,
    ushort* __restrict__ hid_hi)
{
    __shared__ __align__(16) float  As[2][32 * 32];     // 4 KB each, source-pre-swizzled
    __shared__ __align__(16) ushort Bhs[2][4 * 64 * 8]; // 4 KB each, fragment-linear
    __shared__ __align__(16) ushort Bls[2][4 * 64 * 8]; // 4 KB each

    const int b  = blockIdx.y;
    const int s0 = blockIdx.x * 32;
    const int t  = threadIdx.x;
    const int w = t >> 6, lane = t & 63, col = lane & 15, quad = lane >> 4;
    const int rg = w & 1;    // s row-group
    const int ch = w >> 1;   // c half

    const float* hb = hidden + ((size_t)b * SS + s0) * HH;

    // A staging: 4 insts of 1KB (8 rows x 32dw each), 1 per wave.
    // lane -> row = w*8 + (lane>>3), src dword ((lane&7)^(row&7))*4 (pre-swizzled)
    const int st_r8 = lane >> 3;
    const int gA   = (((lane & 7) ^ st_r8) << 2);

    // fragment row owned by this lane
    const int fr  = rg * 16 + col;
    const int idxA = fr * 32 + ((quad * 8) ^ ((fr & 7) << 2));
    ushort* hout = hid_hi + ((size_t)b * SS + s0 + fr) * HH;

    f32x4 acc[2];
    acc[0] = (f32x4){0.f, 0.f, 0.f, 0.f};
    acc[1] = (f32x4){0.f, 0.f, 0.f, 0.f};

#define STAGE(BUF, KS) do { \
    cp16(&As[BUF][w * 8 * 32], hb + (size_t)(w * 8 + st_r8) * HH + (KS) * 32 + gA); \
    cp16(&Bhs[BUF][w * 512], qpkhi + ((size_t)(w * 32 + (KS)) * 64 + lane) * 8); \
    cp16(&Bls[BUF][w * 512], qpklo + ((size_t)(w * 32 + (KS)) * 64 + lane) * 8); } while (0)

    int cur = 0;
    STAGE(0, 0);
    __syncthreads();

    for (int ks = 0; ks < 32; ++ks) {
        if (ks + 1 < 32) STAGE(cur ^ 1, ks + 1);

        const float* Ab = &As[cur][0];
        f32x4 a0 = *(const f32x4*)&Ab[idxA];
        f32x4 a1 = *(const f32x4*)&Ab[idxA ^ 4];
        s16x8 ah, al;
        cvt8(a0, a1, ah, al);
        if (ch == 0) *(s16x8*)&hout[ks * 32 + quad * 8] = ah;
#pragma unroll
        for (int nt = 0; nt < 2; ++nt) {
            const int ng = ch * 2 + nt;
            const s16x8 bh = *(const s16x8*)&Bhs[cur][ng * 512 + lane * 8];
            const s16x8 bl = *(const s16x8*)&Bls[cur][ng * 512 + lane * 8];
            acc[nt] = __builtin_amdgcn_mfma_f32_16x16x32_bf16(ah, bh, acc[nt], 0, 0, 0);
            acc[nt] = __builtin_amdgcn_mfma_f32_16x16x32_bf16(ah, bl, acc[nt], 0, 0, 0);
            acc[nt] = __builtin_amdgcn_mfma_f32_16x16x32_bf16(al, bh, acc[nt], 0, 0, 0);
        }
        __syncthreads();
        cur ^= 1;
    }
#undef STAGE

    // C/D: col -> c (n), quad*4+reg -> s (m)
#pragma unroll
    for (int nt = 0; nt < 2; ++nt) {
        const int c = (ch * 2 + nt) * 16 + col;
        const int s = s0 + rg * 16 + quad * 4;
        *(f32x4*)&scores[((size_t)(b * CC + c)) * SS + s] = acc[nt];
    }
}

// ---------------- softmax over s, writes bf16 factor
__global__ __launch_bounds__(256) void softmax_kernel(
    const float* __restrict__ scores, ushort* __restrict__ factor)
{
    const float* p = scores + (size_t)blockIdx.x * SS;
    ushort* f = factor + (size_t)blockIdx.x * SS;
    const int t = threadIdx.x;
    float4 v[4];
    float m = -3.0e38f;
#pragma unroll
    for (int i = 0; i < 4; ++i) {
        v[i] = *(const float4*)&p[t * 4 + i * 1024];
        m = fmaxf(m, fmaxf(fmaxf(v[i].x, v[i].y), fmaxf(v[i].z, v[i].w)));
    }
#pragma unroll
    for (int off = 1; off < 64; off <<= 1) m = fmaxf(m, __shfl_xor(m, off));
    __shared__ float redm[4];
    __shared__ float reds[4];
    const int wave = t >> 6, lane = t & 63;
    if (lane == 0) redm[wave] = m;
    __syncthreads();
    m = fmaxf(fmaxf(redm[0], redm[1]), fmaxf(redm[2], redm[3]));

    float sum = 0.0f;
#pragma unroll
    for (int i = 0; i < 4; ++i) {
        v[i].x = __expf(v[i].x - m); v[i].y = __expf(v[i].y - m);
        v[i].z = __expf(v[i].z - m); v[i].w = __expf(v[i].w - m);
        sum += (v[i].x + v[i].y) + (v[i].z + v[i].w);
    }
#pragma unroll
    for (int off = 1; off < 64; off <<= 1) sum += __shfl_xor(sum, off);
    if (lane == 0) reds[wave] = sum;
    __syncthreads();
    sum = (reds[0] + reds[1]) + (reds[2] + reds[3]);
    const float inv = 1.0f / sum;
#pragma unroll
    for (int i = 0; i < 4; ++i) {
        ushort4 o;
        o.x = f2bf(v[i].x * inv); o.y = f2bf(v[i].y * inv);
        o.z = f2bf(v[i].z * inv); o.w = f2bf(v[i].w * inv);
        ((ushort4*)f)[t + i * 256] = o;
    }
}

// ---------------- pool: parts[ks8][b][c][h]. 64c x 64h per block, split-8 over S.
// hid_hi staged via global_load_lds into [64 s][64 h] bf16 tiles, XOR-swizzled
// (dword d ^= ((s>>3)&3)<<3) so the perm-transpose reads are bank-conflict-free.
// factor fragments register-prefetched one window ahead. Grid 16x16x8 = 2048 blocks.
__global__ __launch_bounds__(256, 6) void pool_kernel(
    const ushort* __restrict__ hid_hi, const ushort* __restrict__ factor,
    float* __restrict__ parts)
{
    __shared__ __align__(16) ushort Bs[2][64 * 64];  // 8 KB each

    const int b  = blockIdx.y;
    const int h0 = blockIdx.x * 64;
    const int ks8 = blockIdx.z;
    const int sbeg = ks8 * (SS / 8);
    const int t = threadIdx.x;
    const int w = t >> 6, lane = t & 63, col = lane & 15, quad = lane >> 4;

    const ushort* hbase = hid_hi + ((size_t)b * SS + sbeg) * HH + h0;

    f32x4 acc[4];
#pragma unroll
    for (int j = 0; j < 4; ++j) acc[j] = (f32x4){0.f, 0.f, 0.f, 0.f};

    // A-frag (factor): m = c = w*16+col, k = s contiguous
    const ushort* fptr = factor + ((size_t)(b * CC + w * 16 + col)) * SS + sbeg + quad * 8;

    // staging: 8 insts of 1KB (8 s-rows x 128B), 2 per wave.
    // lane -> s = inst*8 + (lane>>3), src chunk (lane&7) ^ ((inst&3)<<1)  [pre-swizzled]
#define PSTAGE(BUF, SC) do { \
    _Pragma("unroll") \
    for (int i = 0; i < 2; ++i) { \
        const int inst = w * 2 + i; \
        cp16(&Bs[BUF][inst * 8 * 64], \
             hbase + (size_t)((SC) + inst * 8 + (lane >> 3)) * HH + \
                 (((lane & 7) ^ ((inst & 3) << 1)) * 8)); \
    } } while (0)

    s16x8 fa0 = *(const s16x8*)&fptr[0];
    s16x8 fa1 = *(const s16x8*)&fptr[32];
    PSTAGE(0, 0);
    __syncthreads();

    int cur = 0;
    for (int sc = 0; sc < SS / 8; sc += 64) {
        s16x8 fn0, fn1;
        if (sc + 64 < SS / 8) {
            PSTAGE(cur ^ 1, sc + 64);
            fn0 = *(const s16x8*)&fptr[sc + 64];
            fn1 = *(const s16x8*)&fptr[sc + 96];
        }

        const u32* B32 = (const u32*)&Bs[cur][0];
#pragma unroll
        for (int ksub = 0; ksub < 2; ++ksub) {
            const s16x8 fa = ksub ? fa1 : fa0;
#pragma unroll
            for (int nt = 0; nt < 4; ++nt) {
                const int h_loc = nt * 16 + col;
                const unsigned sel = (h_loc & 1) ? 0x07060302u : 0x05040100u;
                const int dq = (nt * 8 + (col >> 1)) ^ (quad << 3);  // swizzled dword
                const int base = (ksub * 32 + quad * 8) * 32 + dq;   // row stride = 32 dw
                u32 d0, d1, d2, d3;
                { u32 u0 = B32[base +   0], u1 = B32[base +  32];
                  d0 = __builtin_amdgcn_perm(u1, u0, sel); }
                { u32 u0 = B32[base +  64], u1 = B32[base +  96];
                  d1 = __builtin_amdgcn_perm(u1, u0, sel); }
                { u32 u0 = B32[base + 128], u1 = B32[base + 160];
                  d2 = __builtin_amdgcn_perm(u1, u0, sel); }
                { u32 u0 = B32[base + 192], u1 = B32[base + 224];
                  d3 = __builtin_amdgcn_perm(u1, u0, sel); }
                u32x4 dv = { d0, d1, d2, d3 };
                const s16x8 hbv = __builtin_bit_cast(s16x8, dv);
                acc[nt] = __builtin_amdgcn_mfma_f32_16x16x32_bf16(fa, hbv, acc[nt], 0, 0, 0);
            }
        }
        __syncthreads();
        cur ^= 1;
        fa0 = fn0;
        fa1 = fn1;
    }
#undef PSTAGE

    float* dst = parts + (size_t)ks8 * (BB * CC * HH) + (size_t)b * (CC * HH);
#pragma unroll
    for (int nt = 0; nt < 4; ++nt) {
        const int h = h0 + nt * 16 + col;
#pragma unroll
        for (int r = 0; r < 4; ++r) {
            const int c = w * 16 + quad * 4 + r;
            dst[(size_t)c * HH + h] = acc[nt][r];
        }
    }
}

// ---------------- final reduce of 8 split-K partials
__global__ __launch_bounds__(256) void reduce8_kernel(
    const float* __restrict__ parts, float* __restrict__ out)
{
    const int i = blockIdx.x * 256 + threadIdx.x;   // float4 index, 262144 total
    const float4* p = (const float4*)parts;
    float4 r = {0.f, 0.f, 0.f, 0.f};
#pragma unroll
    for (int k = 0; k < 8; ++k) {
        const float4 a = p[i + (size_t)k * 262144];
        r.x += a.x; r.y += a.y; r.z += a.z; r.w += a.w;
    }
    ((float4*)out)[i] = r;
}

extern "C" void kernel_launch(void* const* d_in, const int* in_sizes, int n_in,
                              void* d_out, int out_size, void* d_ws, size_t ws_size,
                              hipStream_t stream)
{
    const float* hidden = (const float*)d_in[0];   // [16,4096,1024] fp32
    const float* querys = (const float*)d_in[1];   // [64,1024] fp32
    float* out = (float*)d_out;

    float*  scores = (float*)d_ws;                           // 16 MiB [0,16M)
    ushort* factor = (ushort*)((char*)d_ws + (16u << 20));   // 8 MiB  [16M,24M)
    ushort* qpkhi  = (ushort*)((char*)d_ws + (24u << 20));   // 128 KiB
    ushort* qpklo  = qpkhi + 4 * 32 * 64 * 8;                // 128 KiB
    ushort* hid_hi = (ushort*)((char*)d_ws + (32u << 20));   // 128 MiB [32M,160M)
    float*  parts  = (float*)((char*)d_ws + (160u << 20));   // 32 MiB  [160M,192M)

    prep_querys_kernel<<<dim3(32), 256, 0, stream>>>(querys, qpkhi, qpklo);
    scores_kernel<<<dim3(SS / 32, BB), 256, 0, stream>>>(hidden, qpkhi, qpklo, scores, hid_hi);
    softmax_kernel<<<dim3(BB * CC), 256, 0, stream>>>(scores, factor);
    pool_kernel<<<dim3(HH / 64, BB, 8), 256, 0, stream>>>(hid_hi, factor, parts);
    reduce8_kernel<<<dim3(1024), 256, 0, stream>>>(parts, out);
}